// Round 7
// baseline (1180.858 us; speedup 1.0000x reference)
//
#include <hip/hip_runtime.h>

// Batched Jacobi diffusion, B=8, 128x128, iters=1000.
// Round 7: TWO blocks per batch (16 blocks, 16 CUs). Block h owns 64 rows.
// 1024 threads = 32 half-wave groups x 2 rows; lane owns 2x4 cells.
// Per-CU work halves (DS instr 12->8/thread, FMA 64->32/thread, coeff regs
// 64->32). Seam rows (global 63/64) exchanged via global memory with
// device-scope release/acquire flags: parity double-buffered row buffers,
// monotone signed flags (0xAA poison < 0 -> poll `>= it` is poison-safe),
// drift <= 1 by construction. Only the seam half-wave polls.

#define GH 128
#define GW 128
#define NGROUP 32
#define ROWS 2
#define COLS 4
#define NT 1024

__global__ void __launch_bounds__(NT)
__attribute__((amdgpu_waves_per_eu(4, 4)))
jacobi_flux_kernel(const float* __restrict__ k_all,
                   const int* __restrict__ iters_p,
                   float* __restrict__ out,
                   float* __restrict__ ws)
{
    __shared__ __align__(16) float sTop[2][NGROUP][GW];   // 32 KB
    __shared__ __align__(16) float sBot[2][NGROUP][GW];   // 32 KB

    const int b   = blockIdx.x & 7;       // batch
    const int h   = blockIdx.x >> 3;      // half: 0 = rows 0..63, 1 = 64..127
    const int tid = threadIdx.x;
    const int l   = tid & 31;
    const int g   = tid >> 5;
    const int C0  = l * COLS;
    const int R0  = h * 64 + g * ROWS;    // global first row of my tile
    const float* kb = k_all + b * GH * GW;
    const int iters = *iters_p;

    // ---- seam exchange buffers in workspace ----
    // rows: ws[b*512 + h*256 + parity*128 + col]; flags 64B-spaced ints after.
    float*       myBuf  = ws + b * 512 + h * 256;
    const float* nbBuf  = ws + b * 512 + (1 - h) * 256;
    int*         flags  = (int*)(ws + 8 * 512);
    int*         myFlag = flags + b * 32 + h * 16;
    const int*   nbFlag = flags + b * 32 + (1 - h) * 16;
    const bool   isSeam = (h == 0) ? (g == NGROUP - 1) : (g == 0);

    const int lane64 = tid & 63;
    const int idxL = (lane64 - 1) << 2;
    const int idxR = (lane64 + 1) << 2;
    const bool edgeL = (l == 0);
    const bool edgeR = (l == 31);
    const int gUp = (g == 0)          ? 0          : g - 1;
    const int gDn = (g == NGROUP - 1) ? NGROUP - 1 : g + 1;
    const bool gTop = (h == 0 && g == 0);              // global row 0
    const bool gBot = (h == 1 && g == NGROUP - 1);     // global row 127
    const bool seamUp = (h == 1 && g == 0);            // up halo is external
    const bool seamDn = (h == 0 && g == NGROUP - 1);   // dn halo is external

    // ---- one-time: normalized face conductivities (32 regs) ----
    float rN[ROWS][COLS], rS[ROWS][COLS], rW[ROWS][COLS], rE[ROWS][COLS];
    #pragma unroll
    for (int i = 0; i < ROWS; ++i) {
        const int r  = R0 + i;
        const int ru = (r == 0)      ? 0      : r - 1;
        const int rd = (r == GH - 1) ? GH - 1 : r + 1;
        #pragma unroll
        for (int j = 0; j < COLS; ++j) {
            const int c  = C0 + j;
            const int cl = (c == 0)      ? 0      : c - 1;
            const int cr = (c == GW - 1) ? GW - 1 : c + 1;
            float kc = kb[r * GW + c];
            float kn = 0.5f * (kc + kb[ru * GW + c]);
            float ks = 0.5f * (kc + kb[rd * GW + c]);
            float kw = 0.5f * (kc + kb[r * GW + cl]);
            float ke = 0.5f * (kc + kb[r * GW + cr]);
            float inv = 1.0f / (kn + ks + kw + ke);
            rN[i][j] = kn * inv;  rS[i][j] = ks * inv;
            rW[i][j] = kw * inv;  rE[i][j] = ke * inv;
        }
    }

    // ---- state ----
    float A[ROWS][COLS], B[ROWS][COLS];
    float lfA[ROWS], rtA[ROWS], lfB[ROWS], rtB[ROWS];
    float extH[COLS] = {0.0f, 0.0f, 0.0f, 0.0f};   // seam halo @ state 0 = 0

    #pragma unroll
    for (int i = 0; i < ROWS; ++i)
        #pragma unroll
        for (int j = 0; j < COLS; ++j)
            A[i][j] = (R0 + i == 0) ? 1.0f : 0.0f;

    // prime set 0 + horizontal neighbors of A
    *(float4*)&sTop[0][g][C0] = make_float4(A[0][0], A[0][1], A[0][2], A[0][3]);
    *(float4*)&sBot[0][g][C0] = make_float4(A[1][0], A[1][1], A[1][2], A[1][3]);
    #pragma unroll
    for (int i = 0; i < ROWS; ++i) {
        float fL = __int_as_float(__builtin_amdgcn_ds_bpermute(idxL, __float_as_int(A[i][COLS-1])));
        float fR = __int_as_float(__builtin_amdgcn_ds_bpermute(idxR, __float_as_int(A[i][0])));
        lfA[i] = edgeL ? A[i][0]      : fL;
        rtA[i] = edgeR ? A[i][COLS-1] : fR;
    }
    __syncthreads();

    auto step = [&](const float (&src)[ROWS][COLS], float (&dst)[ROWS][COLS],
                    const float (&lfS)[ROWS], const float (&rtS)[ROWS],
                    float (&lfD)[ROWS], float (&rtD)[ROWS],
                    int rp, int wp, int it) {
        // seam: fetch neighbor row @ state it (published by nb at end of it-1)
        if (isSeam && it > 0) {
            while (__hip_atomic_load(nbFlag, __ATOMIC_ACQUIRE,
                                     __HIP_MEMORY_SCOPE_AGENT) < it) {}
            float4 e = *(const float4*)(nbBuf + (it & 1) * GW + C0);
            extH[0] = e.x; extH[1] = e.y; extH[2] = e.z; extH[3] = e.w;
        }
        // LDS halos
        float4 hu = *(const float4*)&sBot[rp][gUp][C0];
        float4 hd = *(const float4*)&sTop[rp][gDn][C0];
        float huA[COLS] = {hu.x, hu.y, hu.z, hu.w};
        float hdA[COLS] = {hd.x, hd.y, hd.z, hd.w};
        if (seamUp) {
            #pragma unroll
            for (int j = 0; j < COLS; ++j) huA[j] = extH[j];
        }
        if (seamDn) {
            #pragma unroll
            for (int j = 0; j < COLS; ++j) hdA[j] = extH[j];
        }
        // compute both rows
        #pragma unroll
        for (int j = 0; j < COLS; ++j) {
            float lf0 = (j == 0)        ? lfS[0] : src[0][j - 1];
            float rt0 = (j == COLS - 1) ? rtS[0] : src[0][j + 1];
            dst[0][j] = fmaf(rN[0][j], huA[j],
                        fmaf(rS[0][j], src[1][j],
                        fmaf(rW[0][j], lf0, rE[0][j] * rt0)));
            float lf1 = (j == 0)        ? lfS[1] : src[1][j - 1];
            float rt1 = (j == COLS - 1) ? rtS[1] : src[1][j + 1];
            dst[1][j] = fmaf(rN[1][j], src[0][j],
                        fmaf(rS[1][j], hdA[j],
                        fmaf(rW[1][j], lf1, rE[1][j] * rt1)));
        }
        if (gTop) {
            #pragma unroll
            for (int j = 0; j < COLS; ++j) dst[0][j] = 1.0f;
        }
        if (gBot) {
            #pragma unroll
            for (int j = 0; j < COLS; ++j) dst[1][j] = 0.0f;
        }
        // seam publish (issue global store early)
        if (isSeam) {
            float4 v = (h == 0)
                ? make_float4(dst[1][0], dst[1][1], dst[1][2], dst[1][3])   // row 63
                : make_float4(dst[0][0], dst[0][1], dst[0][2], dst[0][3]);  // row 64
            *(float4*)(myBuf + ((it + 1) & 1) * GW + C0) = v;
            if (l == 0)
                __hip_atomic_store(myFlag, it + 1, __ATOMIC_RELEASE,
                                   __HIP_MEMORY_SCOPE_AGENT);
        }
        // horizontal neighbors for next iter (own-wave bpermute on new vals)
        #pragma unroll
        for (int i = 0; i < ROWS; ++i) {
            float fL = __int_as_float(__builtin_amdgcn_ds_bpermute(idxL, __float_as_int(dst[i][COLS-1])));
            float fR = __int_as_float(__builtin_amdgcn_ds_bpermute(idxR, __float_as_int(dst[i][0])));
            lfD[i] = edgeL ? dst[i][0]      : fL;
            rtD[i] = edgeR ? dst[i][COLS-1] : fR;
        }
        // LDS publish
        *(float4*)&sTop[wp][g][C0] = make_float4(dst[0][0], dst[0][1], dst[0][2], dst[0][3]);
        *(float4*)&sBot[wp][g][C0] = make_float4(dst[1][0], dst[1][1], dst[1][2], dst[1][3]);
        __syncthreads();
    };

    const int nPairs = iters >> 1;
    for (int itp = 0; itp < nPairs; ++itp) {
        step(A, B, lfA, rtA, lfB, rtB, 0, 1, 2 * itp);
        step(B, A, lfB, rtB, lfA, rtA, 1, 0, 2 * itp + 1);
    }
    if (iters & 1) {
        step(A, B, lfA, rtA, lfB, rtB, 0, 1, iters - 1);
        #pragma unroll
        for (int i = 0; i < ROWS; ++i)
            #pragma unroll
            for (int j = 0; j < COLS; ++j)
                A[i][j] = B[i][j];
    }

    // ---- flux at row 64: block h=1, g=0 holds rows 64 (A[0]) and 65 (A[1]) ----
    if (h == 1 && g == 0) {
        float partial = 0.0f;
        #pragma unroll
        for (int j = 0; j < COLS; ++j)
            partial -= kb[64 * GW + C0 + j] * (A[1][j] - A[0][j]);
        #pragma unroll
        for (int off = 16; off > 0; off >>= 1)
            partial += __shfl_down(partial, off, 32);
        if (l == 0) out[b] = partial;
    }
}

extern "C" void kernel_launch(void* const* d_in, const int* in_sizes, int n_in,
                              void* d_out, int out_size, void* d_ws, size_t ws_size,
                              hipStream_t stream)
{
    const float* k     = (const float*)d_in[0];
    const int*   iters = (const int*)d_in[1];
    float*       out   = (float*)d_out;
    float*       ws    = (float*)d_ws;     // needs ~17.4 KB: rows + flags
    jacobi_flux_kernel<<<dim3(16), dim3(NT), 0, stream>>>(k, iters, out, ws);
}

// Round 8
// 797.980 us; speedup vs baseline: 1.4798x; 1.4798x over previous
//
#include <hip/hip_runtime.h>

// Batched Jacobi diffusion, B=8, 128x128, iters=1000. One 1024-thread block
// per batch (reverted from round-7 2-CU split: cross-CU seam sync cost
// ~800 cyc/iter of unhidden L2 round-trip).
// 32 half-wave groups x 4 rows; lane owns 4x4 cells.
// Round 8: horizontal lane+-1 exchange via DPP wave shifts (VALU pipe,
// wave_shr:1=0x138 / wave_shl:1=0x130) instead of ds_bpermute -> DS instr
// per thread-iter drops 12 -> 4 (only the vertical b128 halo ops remain).
// Group-seam lanes (l==0/31) are exactly the lanes DPP feeds invalid or
// cross-group data, and they were already cndmask-clamped to the grid edge.
//   post-barrier: 2 ds_read_b128 halo reads + all FMA
//   pre-barrier:  8 DPP shifts on NEW values + 2 ds_write_b128 publishes
// 1 barrier/iter, 2x-unrolled register ping-pong.

#define GH 128
#define GW 128
#define NGROUP 32
#define ROWS 4
#define COLS 4
#define NT 1024

__device__ __forceinline__ float dpp_from_left(float x) {
    // lane l gets lane l-1's x (wave_shr:1); invalid lane 0 keeps own x
    return __int_as_float(__builtin_amdgcn_update_dpp(
        __float_as_int(x), __float_as_int(x), 0x138, 0xf, 0xf, false));
}
__device__ __forceinline__ float dpp_from_right(float x) {
    // lane l gets lane l+1's x (wave_shl:1); invalid lane 63 keeps own x
    return __int_as_float(__builtin_amdgcn_update_dpp(
        __float_as_int(x), __float_as_int(x), 0x130, 0xf, 0xf, false));
}

__global__ void __launch_bounds__(NT)
jacobi_flux_kernel(const float* __restrict__ k_all,
                   const int* __restrict__ iters_p,
                   float* __restrict__ out)
{
    __shared__ __align__(16) float sTop[2][NGROUP][GW];   // 32 KB
    __shared__ __align__(16) float sBot[2][NGROUP][GW];   // 32 KB

    const int b   = blockIdx.x;
    const int tid = threadIdx.x;
    const int l   = tid & 31;
    const int g   = tid >> 5;
    const int C0  = l * COLS;
    const int R0  = g * ROWS;
    const float* kb = k_all + b * GH * GW;
    const int iters = *iters_p;

    const bool edgeL = (l == 0);
    const bool edgeR = (l == 31);
    const int gUp = (g == 0)          ? 0          : g - 1;
    const int gDn = (g == NGROUP - 1) ? NGROUP - 1 : g + 1;
    const bool gTop = (g == 0);
    const bool gBot = (g == NGROUP - 1);

    // ---- one-time: normalized face conductivities ----
    float rN[ROWS][COLS], rS[ROWS][COLS], rW[ROWS][COLS], rE[ROWS][COLS];
    #pragma unroll
    for (int i = 0; i < ROWS; ++i) {
        const int r  = R0 + i;
        const int ru = (r == 0)      ? 0      : r - 1;
        const int rd = (r == GH - 1) ? GH - 1 : r + 1;
        #pragma unroll
        for (int j = 0; j < COLS; ++j) {
            const int c  = C0 + j;
            const int cl = (c == 0)      ? 0      : c - 1;
            const int cr = (c == GW - 1) ? GW - 1 : c + 1;
            float kc = kb[r * GW + c];
            float kn = 0.5f * (kc + kb[ru * GW + c]);
            float ks = 0.5f * (kc + kb[rd * GW + c]);
            float kw = 0.5f * (kc + kb[r * GW + cl]);
            float ke = 0.5f * (kc + kb[r * GW + cr]);
            float inv = 1.0f / (kn + ks + kw + ke);
            rN[i][j] = kn * inv;  rS[i][j] = ks * inv;
            rW[i][j] = kw * inv;  rE[i][j] = ke * inv;
        }
    }

    // ---- state: ping-pong register tiles ----
    float A[ROWS][COLS], B[ROWS][COLS];
    float lfA[ROWS], rtA[ROWS], lfB[ROWS], rtB[ROWS];

    #pragma unroll
    for (int i = 0; i < ROWS; ++i)
        #pragma unroll
        for (int j = 0; j < COLS; ++j)
            A[i][j] = (R0 + i == 0) ? 1.0f : 0.0f;

    // prime: publish A's boundary rows into set 0, horizontal neighbors of A
    *(float4*)&sTop[0][g][C0] = make_float4(A[0][0], A[0][1], A[0][2], A[0][3]);
    *(float4*)&sBot[0][g][C0] = make_float4(A[ROWS-1][0], A[ROWS-1][1], A[ROWS-1][2], A[ROWS-1][3]);
    #pragma unroll
    for (int i = 0; i < ROWS; ++i) {
        float fL = dpp_from_left(A[i][COLS-1]);
        float fR = dpp_from_right(A[i][0]);
        lfA[i] = edgeL ? A[i][0]        : fL;
        rtA[i] = edgeR ? A[i][COLS-1]   : fR;
    }
    __syncthreads();

    auto step = [&](const float (&src)[ROWS][COLS], float (&dst)[ROWS][COLS],
                    const float (&lfS)[ROWS], const float (&rtS)[ROWS],
                    float (&lfD)[ROWS], float (&rtD)[ROWS],
                    int rp, int wp) {
        // halo reads issued first (latency hidden under interior FMAs)
        float4 hu = *(const float4*)&sBot[rp][gUp][C0];   // row R0-1
        float4 hd = *(const float4*)&sTop[rp][gDn][C0];   // row R0+ROWS

        // interior rows 1..ROWS-2: register-only
        #pragma unroll
        for (int i = 1; i < ROWS - 1; ++i) {
            #pragma unroll
            for (int j = 0; j < COLS; ++j) {
                float lf = (j == 0)        ? lfS[i] : src[i][j - 1];
                float rt = (j == COLS - 1) ? rtS[i] : src[i][j + 1];
                dst[i][j] = fmaf(rN[i][j], src[i - 1][j],
                            fmaf(rS[i][j], src[i + 1][j],
                            fmaf(rW[i][j], lf, rE[i][j] * rt)));
            }
        }
        // boundary rows (consume halo)
        float huA[COLS] = {hu.x, hu.y, hu.z, hu.w};
        float hdA[COLS] = {hd.x, hd.y, hd.z, hd.w};
        #pragma unroll
        for (int j = 0; j < COLS; ++j) {
            float lf0 = (j == 0)        ? lfS[0] : src[0][j - 1];
            float rt0 = (j == COLS - 1) ? rtS[0] : src[0][j + 1];
            dst[0][j] = fmaf(rN[0][j], huA[j],
                        fmaf(rS[0][j], src[1][j],
                        fmaf(rW[0][j], lf0, rE[0][j] * rt0)));
            float lf3 = (j == 0)        ? lfS[ROWS-1] : src[ROWS-1][j - 1];
            float rt3 = (j == COLS - 1) ? rtS[ROWS-1] : src[ROWS-1][j + 1];
            dst[ROWS-1][j] = fmaf(rN[ROWS-1][j], src[ROWS-2][j],
                             fmaf(rS[ROWS-1][j], hdA[j],
                             fmaf(rW[ROWS-1][j], lf3, rE[ROWS-1][j] * rt3)));
        }
        if (gTop) {
            #pragma unroll
            for (int j = 0; j < COLS; ++j) dst[0][j] = 1.0f;
        }
        if (gBot) {
            #pragma unroll
            for (int j = 0; j < COLS; ++j) dst[ROWS-1][j] = 0.0f;
        }
        // pre-barrier: next-iter horizontal neighbors via DPP (VALU pipe)
        #pragma unroll
        for (int i = 0; i < ROWS; ++i) {
            float fL = dpp_from_left(dst[i][COLS-1]);
            float fR = dpp_from_right(dst[i][0]);
            lfD[i] = edgeL ? dst[i][0]        : fL;
            rtD[i] = edgeR ? dst[i][COLS-1]   : fR;
        }
        // publish boundary rows
        *(float4*)&sTop[wp][g][C0] = make_float4(dst[0][0], dst[0][1], dst[0][2], dst[0][3]);
        *(float4*)&sBot[wp][g][C0] = make_float4(dst[ROWS-1][0], dst[ROWS-1][1], dst[ROWS-1][2], dst[ROWS-1][3]);
        __syncthreads();
    };

    const int nPairs = iters >> 1;
    for (int it = 0; it < nPairs; ++it) {
        step(A, B, lfA, rtA, lfB, rtB, 0, 1);
        step(B, A, lfB, rtB, lfA, rtA, 1, 0);
    }
    if (iters & 1) {
        step(A, B, lfA, rtA, lfB, rtB, 0, 1);
        #pragma unroll
        for (int i = 0; i < ROWS; ++i)
            #pragma unroll
            for (int j = 0; j < COLS; ++j)
                A[i][j] = B[i][j];
    }

    // ---- flux at row 64: group 16 holds rows 64..67 (A[0]=r64, A[1]=r65) ----
    if (g == 16) {
        float partial = 0.0f;
        #pragma unroll
        for (int j = 0; j < COLS; ++j)
            partial -= kb[64 * GW + C0 + j] * (A[1][j] - A[0][j]);
        #pragma unroll
        for (int off = 16; off > 0; off >>= 1)
            partial += __shfl_down(partial, off, 32);
        if (l == 0) out[b] = partial;
    }
}

extern "C" void kernel_launch(void* const* d_in, const int* in_sizes, int n_in,
                              void* d_out, int out_size, void* d_ws, size_t ws_size,
                              hipStream_t stream)
{
    const float* k     = (const float*)d_in[0];
    const int*   iters = (const int*)d_in[1];
    float*       out   = (float*)d_out;
    jacobi_flux_kernel<<<dim3(8), dim3(NT), 0, stream>>>(k, iters, out);
}